// Round 1
// baseline (365.573 us; speedup 1.0000x reference)
//
#include <hip/hip_runtime.h>

// Problem sizes (fixed by the reference)
#define NN 512   // graph nodes
#define DD 768   // feature dim (= output dim)
#define BB 32    // batch

typedef __bf16 bf16;
typedef bf16 bf16x8 __attribute__((ext_vector_type(8)));
typedef bf16 bf16x4 __attribute__((ext_vector_type(4)));
typedef float f32x4 __attribute__((ext_vector_type(4)));

typedef const unsigned int __attribute__((address_space(1)))* gas_cuintp;
typedef unsigned int __attribute__((address_space(3)))* las_uintp;

__device__ __forceinline__ void async_copy16(const void* g, void* l) {
    __builtin_amdgcn_global_load_lds((gas_cuintp)g, (las_uintp)l, 16, 0, 0);
}

// ---------------------------------------------------------------------------
// Prep kernels
// ---------------------------------------------------------------------------

// d[i] = (sum_j (adj[i,j]) + 1)^(-1/2)
__global__ void k_rowsum(const float* __restrict__ adj, float* __restrict__ dv) {
    const int i = blockIdx.x;
    const int lane = threadIdx.x;  // 64 threads
    float s = 0.f;
#pragma unroll
    for (int j = 0; j < NN / 64; ++j) s += adj[(size_t)i * NN + lane + j * 64];
#pragma unroll
    for (int off = 32; off; off >>= 1) s += __shfl_down(s, off);
    if (lane == 0) dv[i] = rsqrtf(s + 1.0f);
}

// Sb[n,k] = bf16( (adj[k,n] + (n==k)) * dv[n] * dv[k] )   (support[n,k])
__global__ void k_support(const float* __restrict__ adj, const float* __restrict__ dv,
                          bf16* __restrict__ sb) {
    const int idx = blockIdx.x * 256 + threadIdx.x;  // 512*512 total
    const int n = idx >> 9, k = idx & 511;
    float m = adj[(size_t)k * NN + n] + (n == k ? 1.0f : 0.0f);
    sb[idx] = (bf16)(m * dv[n] * dv[k]);
}

// Wt[m][o][d] = bf16( weights[d*4+m][o] )
__global__ void k_prepwt(const float* __restrict__ w, bf16* __restrict__ wt) {
    const int idx = blockIdx.x * 256 + threadIdx.x;  // 4*768*768
    if (idx >= 4 * DD * DD) return;
    const int m = idx / (DD * DD);
    const int rem = idx % (DD * DD);
    const int o = rem / DD;
    const int d = rem % DD;
    wt[idx] = (bf16)w[(size_t)(d * 4 + m) * DD + o];
}

// straight cast inputs f32 [B][N][D] -> bf16 Xrow0 [B][N][D]
__global__ void k_cast(const float* __restrict__ in, bf16* __restrict__ outp, int n4) {
    int idx = blockIdx.x * blockDim.x + threadIdx.x;
    const int stride = gridDim.x * blockDim.x;
    for (int i = idx; i < n4; i += stride) {
        f32x4 v = ((const f32x4*)in)[i];
        bf16x4 p;
#pragma unroll
        for (int j = 0; j < 4; ++j) p[j] = (bf16)v[j];
        ((bf16x4*)outp)[i] = p;
    }
}

// transpose-cast inputs f32 [B][N][D] -> bf16 XT0 [B][D][N]
__global__ void k_transpose(const float* __restrict__ in, bf16* __restrict__ xt) {
    __shared__ float tile[32][33];
    const int b = blockIdx.z;
    const int d0 = blockIdx.x * 32;
    const int n0 = blockIdx.y * 32;
    const int x = threadIdx.x;  // 32
    const int y = threadIdx.y;  // 8
    const float* ib = in + (size_t)b * NN * DD;
#pragma unroll
    for (int q = 0; q < 4; ++q)
        tile[y + q * 8][x] = ib[(size_t)(n0 + y + q * 8) * DD + d0 + x];
    __syncthreads();
    bf16* ob = xt + (size_t)b * DD * NN;
#pragma unroll
    for (int q = 0; q < 4; ++q)
        ob[(size_t)(d0 + y + q * 8) * NN + n0 + x] = (bf16)tile[x][y + q * 8];
}

// ---------------------------------------------------------------------------
// Diffusion GEMM:  C[i=d][j=n] = sum_k XT[b][d][k] * Sb[n][k]   (bt-form)
// epilogue: v = alpha*acc - (useprev2 ? prev2[d][n] : 0)
// writes XT_m [b][d][n] (optional, may alias prev2 in-place) and Xrow_m [b][n][d]
// ---------------------------------------------------------------------------
__global__ __launch_bounds__(256)
void k_gemm_diff(const bf16* __restrict__ A, const bf16* __restrict__ Sb,
                 const bf16* prev2, bf16* xtOut, bf16* __restrict__ xrow,
                 float alpha, int useprev2) {
    __shared__ bf16 At[128 * 32] __attribute__((aligned(16)));
    __shared__ bf16 Bt[128 * 32] __attribute__((aligned(16)));
    const int b = blockIdx.z;
    const int i0 = blockIdx.y * 128;  // d rows (768)
    const int j0 = blockIdx.x * 128;  // n cols (512)
    const int t = threadIdx.x;
    const int lane = t & 63;
    const int w = t >> 6;
    const int wr = w >> 1, wc = w & 1;
    const int srow = t >> 2;
    const int scol = (t & 3) * 8;
    const bf16* Ab = A + (size_t)b * (DD * NN);

    f32x4 acc[4][4];
#pragma unroll
    for (int mi = 0; mi < 4; ++mi)
#pragma unroll
        for (int ni = 0; ni < 4; ++ni) acc[mi][ni] = f32x4{0.f, 0.f, 0.f, 0.f};

    const int fr = lane & 15;
    const int fk = (lane >> 4) * 8;

    for (int k0 = 0; k0 < NN; k0 += 32) {
        __syncthreads();
        async_copy16(Ab + (size_t)(i0 + srow) * NN + k0 + scol, &At[t * 8]);
        async_copy16(Ab + (size_t)(i0 + 64 + srow) * NN + k0 + scol, &At[2048 + t * 8]);
        async_copy16(Sb + (size_t)(j0 + srow) * NN + k0 + scol, &Bt[t * 8]);
        async_copy16(Sb + (size_t)(j0 + 64 + srow) * NN + k0 + scol, &Bt[2048 + t * 8]);
        __syncthreads();
        bf16x8 af[4], bg[4];
#pragma unroll
        for (int mi = 0; mi < 4; ++mi)
            af[mi] = *(const bf16x8*)&At[(wr * 64 + mi * 16 + fr) * 32 + fk];
#pragma unroll
        for (int ni = 0; ni < 4; ++ni)
            bg[ni] = *(const bf16x8*)&Bt[(wc * 64 + ni * 16 + fr) * 32 + fk];
#pragma unroll
        for (int mi = 0; mi < 4; ++mi)
#pragma unroll
            for (int ni = 0; ni < 4; ++ni)
                acc[mi][ni] = __builtin_amdgcn_mfma_f32_16x16x32_bf16(
                    af[mi], bg[ni], acc[mi][ni], 0, 0, 0);
    }

    const int rb = (lane >> 4) * 4;
    const size_t xtBase = (size_t)b * (DD * NN);
    const size_t xrBase = (size_t)b * (NN * DD);
#pragma unroll
    for (int mi = 0; mi < 4; ++mi) {
#pragma unroll
        for (int ni = 0; ni < 4; ++ni) {
            const int ii = i0 + wr * 64 + mi * 16 + rb;  // d
            const int jj = j0 + wc * 64 + ni * 16 + fr;  // n
            float v[4];
#pragma unroll
            for (int tt = 0; tt < 4; ++tt) {
                float x = alpha * acc[mi][ni][tt];
                if (useprev2) x -= (float)prev2[xtBase + (size_t)(ii + tt) * NN + jj];
                v[tt] = x;
            }
            if (xtOut) {
#pragma unroll
                for (int tt = 0; tt < 4; ++tt)
                    xtOut[xtBase + (size_t)(ii + tt) * NN + jj] = (bf16)v[tt];
            }
            bf16x4 p;
#pragma unroll
            for (int tt = 0; tt < 4; ++tt) p[tt] = (bf16)v[tt];
            *(bf16x4*)&xrow[xrBase + (size_t)jj * DD + ii] = p;
        }
    }
}

// ---------------------------------------------------------------------------
// Final GEMM: out[bn][o] = sum_s sum_d Xrow_s[bn][d] * Wt[s][o][d]  (+bias)
// ---------------------------------------------------------------------------
__global__ __launch_bounds__(256)
void k_gemm_final(const bf16* x0, const bf16* x1, const bf16* x2, const bf16* x3,
                  const bf16* __restrict__ Wt, const float* __restrict__ bias,
                  float* __restrict__ out, int nslabs, int accum, int addbias) {
    __shared__ bf16 At[128 * 32] __attribute__((aligned(16)));
    __shared__ bf16 Bt[128 * 32] __attribute__((aligned(16)));
    const int i0 = blockIdx.y * 128;  // bn rows (16384)
    const int j0 = blockIdx.x * 128;  // o cols (768)
    const int t = threadIdx.x;
    const int lane = t & 63;
    const int w = t >> 6;
    const int wr = w >> 1, wc = w & 1;
    const int srow = t >> 2;
    const int scol = (t & 3) * 8;
    const bf16* slabs[4] = {x0, x1, x2, x3};

    f32x4 acc[4][4];
#pragma unroll
    for (int mi = 0; mi < 4; ++mi)
#pragma unroll
        for (int ni = 0; ni < 4; ++ni) acc[mi][ni] = f32x4{0.f, 0.f, 0.f, 0.f};

    const int fr = lane & 15;
    const int fk = (lane >> 4) * 8;

    for (int s = 0; s < nslabs; ++s) {
        const bf16* As = slabs[s];
        const bf16* Bs = Wt + (size_t)s * (DD * DD);
        for (int k0 = 0; k0 < DD; k0 += 32) {
            __syncthreads();
            async_copy16(As + (size_t)(i0 + srow) * DD + k0 + scol, &At[t * 8]);
            async_copy16(As + (size_t)(i0 + 64 + srow) * DD + k0 + scol, &At[2048 + t * 8]);
            async_copy16(Bs + (size_t)(j0 + srow) * DD + k0 + scol, &Bt[t * 8]);
            async_copy16(Bs + (size_t)(j0 + 64 + srow) * DD + k0 + scol, &Bt[2048 + t * 8]);
            __syncthreads();
            bf16x8 af[4], bg[4];
#pragma unroll
            for (int mi = 0; mi < 4; ++mi)
                af[mi] = *(const bf16x8*)&At[(wr * 64 + mi * 16 + fr) * 32 + fk];
#pragma unroll
            for (int ni = 0; ni < 4; ++ni)
                bg[ni] = *(const bf16x8*)&Bt[(wc * 64 + ni * 16 + fr) * 32 + fk];
#pragma unroll
            for (int mi = 0; mi < 4; ++mi)
#pragma unroll
                for (int ni = 0; ni < 4; ++ni)
                    acc[mi][ni] = __builtin_amdgcn_mfma_f32_16x16x32_bf16(
                        af[mi], bg[ni], acc[mi][ni], 0, 0, 0);
        }
    }

    const int rb = (lane >> 4) * 4;
#pragma unroll
    for (int ni = 0; ni < 4; ++ni) {
        const int jj = j0 + wc * 64 + ni * 16 + fr;  // o
        const float bv = addbias ? bias[jj] : 0.f;
#pragma unroll
        for (int mi = 0; mi < 4; ++mi) {
            const int ii = i0 + wr * 64 + mi * 16 + rb;  // bn
#pragma unroll
            for (int tt = 0; tt < 4; ++tt) {
                const size_t idx = (size_t)(ii + tt) * DD + jj;
                float x = acc[mi][ni][tt] + bv;
                if (accum) x += out[idx];
                out[idx] = x;
            }
        }
    }
}

// ---------------------------------------------------------------------------
// Launch
// ---------------------------------------------------------------------------
extern "C" void kernel_launch(void* const* d_in, const int* in_sizes, int n_in,
                              void* d_out, int out_size, void* d_ws, size_t ws_size,
                              hipStream_t stream) {
    const float* inputs = (const float*)d_in[0];   // [32,512,768]
    const float* adj = (const float*)d_in[1];      // [512,512]
    const float* weights = (const float*)d_in[2];  // [3072,768]
    const float* biases = (const float*)d_in[3];   // [768]
    float* out = (float*)d_out;                    // [32,512,768]

    char* ws = (char*)d_ws;
    const size_t SLAB = (size_t)BB * DD * NN * 2;  // 25165824 B, bf16 slab
    float* dv = (float*)ws;                        // 2048 B
    bf16* Sb = (bf16*)(ws + 2048);                 // 512 KiB
    bf16* Wt = (bf16*)(ws + 526336);               // 4.5 MiB
    char* slabBase = ws + 5244928;
    bf16* XTa = (bf16*)(slabBase);
    bf16* XTb = (bf16*)(slabBase + SLAB);
    bf16* Xr0 = (bf16*)(slabBase + 2 * SLAB);
    const size_t needA = 5244928 + 6 * SLAB;  // ~149 MiB
    const bool bigPath = ws_size >= needA;
    bf16* Xr1 = bigPath ? (bf16*)(slabBase + 3 * SLAB) : Xr0;
    bf16* Xr2 = bigPath ? (bf16*)(slabBase + 4 * SLAB) : Xr0;
    bf16* Xr3 = bigPath ? (bf16*)(slabBase + 5 * SLAB) : Xr0;

    // Prep
    k_rowsum<<<NN, 64, 0, stream>>>(adj, dv);
    k_support<<<(NN * NN) / 256, 256, 0, stream>>>(adj, dv, Sb);
    k_prepwt<<<(4 * DD * DD) / 256, 256, 0, stream>>>(weights, Wt);
    k_cast<<<2048, 256, 0, stream>>>(inputs, Xr0, (BB * NN * DD) / 4);
    k_transpose<<<dim3(DD / 32, NN / 32, BB), dim3(32, 8), 0, stream>>>(inputs, XTa);

    const dim3 dgrid(NN / 128, DD / 128, BB);  // (4,6,32)
    const dim3 fgrid(DD / 128, (BB * NN) / 128);  // (6,128)

    if (bigPath) {
        // x1 = S@x0                  -> XTb, Xr1
        k_gemm_diff<<<dgrid, 256, 0, stream>>>(XTa, Sb, nullptr, XTb, Xr1, 1.0f, 0);
        // x2 = 2*S@x1 - x0           -> XTa (in-place over x0), Xr2
        k_gemm_diff<<<dgrid, 256, 0, stream>>>(XTb, Sb, XTa, XTa, Xr2, 2.0f, 1);
        // x3 = 2*S@x2 - x1           -> Xr3 only
        k_gemm_diff<<<dgrid, 256, 0, stream>>>(XTa, Sb, XTb, nullptr, Xr3, 2.0f, 1);
        // out = [x0|x1|x2|x3] @ W + b
        k_gemm_final<<<fgrid, 256, 0, stream>>>(Xr0, Xr1, Xr2, Xr3, Wt, biases, out, 4, 0, 1);
    } else {
        // Low-workspace path: accumulate 4 partial GEMMs into out
        k_gemm_final<<<fgrid, 256, 0, stream>>>(Xr0, Xr0, Xr0, Xr0, Wt, biases, out, 1, 0, 1);
        k_gemm_diff<<<dgrid, 256, 0, stream>>>(XTa, Sb, nullptr, XTb, Xr0, 1.0f, 0);
        k_gemm_final<<<fgrid, 256, 0, stream>>>(Xr0, Xr0, Xr0, Xr0, Wt + (size_t)1 * DD * DD,
                                                biases, out, 1, 1, 0);
        k_gemm_diff<<<dgrid, 256, 0, stream>>>(XTb, Sb, XTa, XTa, Xr0, 2.0f, 1);
        k_gemm_final<<<fgrid, 256, 0, stream>>>(Xr0, Xr0, Xr0, Xr0, Wt + (size_t)2 * DD * DD,
                                                biases, out, 1, 1, 0);
        k_gemm_diff<<<dgrid, 256, 0, stream>>>(XTa, Sb, XTb, nullptr, Xr0, 2.0f, 1);
        k_gemm_final<<<fgrid, 256, 0, stream>>>(Xr0, Xr0, Xr0, Xr0, Wt + (size_t)3 * DD * DD,
                                                biases, out, 1, 1, 0);
    }
}

// Round 3
// 300.376 us; speedup vs baseline: 1.2171x; 1.2171x over previous
//
#include <hip/hip_runtime.h>

// Problem sizes (fixed by the reference)
#define NN 512   // graph nodes
#define DD 768   // feature dim (= output dim)
#define BB 32    // batch

typedef __bf16 bf16;
typedef bf16 bf16x8 __attribute__((ext_vector_type(8)));
typedef bf16 bf16x4 __attribute__((ext_vector_type(4)));
typedef float f32x4 __attribute__((ext_vector_type(4)));

typedef const unsigned int __attribute__((address_space(1)))* gas_cuintp;
typedef unsigned int __attribute__((address_space(3)))* las_uintp;

__device__ __forceinline__ void async_copy16(const void* g, void* l) {
    __builtin_amdgcn_global_load_lds((gas_cuintp)g, (las_uintp)l, 16, 0, 0);
}

// ---------------------------------------------------------------------------
// Prep kernels
// ---------------------------------------------------------------------------

__global__ void k_rowsum(const float* __restrict__ adj, float* __restrict__ dv) {
    const int i = blockIdx.x;
    const int lane = threadIdx.x;  // 64
    float s = 0.f;
#pragma unroll
    for (int j = 0; j < NN / 64; ++j) s += adj[(size_t)i * NN + lane + j * 64];
#pragma unroll
    for (int off = 32; off; off >>= 1) s += __shfl_down(s, off);
    if (lane == 0) dv[i] = rsqrtf(s + 1.0f);
}

// support[n,k] = (adj[k,n] + (n==k)) * dv[n] * dv[k]; writes Sb[n][k] and SbT[k][n]
__global__ void k_support2(const float* __restrict__ adj, const float* __restrict__ dv,
                           bf16* __restrict__ sb, bf16* __restrict__ sbt) {
    __shared__ bf16 tile[32][33];
    const int k0 = blockIdx.y * 32;
    const int n0 = blockIdx.x * 32;
    const int x = threadIdx.x;
    const int y = threadIdx.y;
    const float dn = dv[n0 + x];
#pragma unroll
    for (int q = 0; q < 4; ++q) {
        const int k = k0 + y + q * 8;
        float m = adj[(size_t)k * NN + n0 + x] + ((k == n0 + x) ? 1.0f : 0.0f);
        bf16 v = (bf16)(m * dn * dv[k]);
        sbt[(size_t)k * NN + n0 + x] = v;
        tile[y + q * 8][x] = v;
    }
    __syncthreads();
#pragma unroll
    for (int q = 0; q < 4; ++q)
        sb[(size_t)(n0 + y + q * 8) * NN + k0 + x] = tile[x][y + q * 8];
}

// Wt[m][o][d] = w[d*4+m][o]
__global__ void k_prepwt2(const float* __restrict__ w, bf16* __restrict__ wt) {
    __shared__ bf16 tile[32][33];
    const int m = blockIdx.z;
    const int d0 = blockIdx.y * 32;
    const int o0 = blockIdx.x * 32;
    const int x = threadIdx.x, y = threadIdx.y;
#pragma unroll
    for (int q = 0; q < 4; ++q) {
        const int d = d0 + y + q * 8;
        tile[y + q * 8][x] = (bf16)w[(size_t)(d * 4 + m) * DD + o0 + x];
    }
    __syncthreads();
    bf16* wm = wt + (size_t)m * DD * DD;
#pragma unroll
    for (int q = 0; q < 4; ++q)
        wm[(size_t)(o0 + y + q * 8) * DD + d0 + x] = tile[x][y + q * 8];
}

// fused: f32 [b][n][d] -> Xr0 bf16 [b][n][d] AND XT0 bf16 [b][d][n]
__global__ __launch_bounds__(256) void k_prepx(const float* __restrict__ in,
                                               bf16* __restrict__ xr,
                                               bf16* __restrict__ xt) {
    __shared__ bf16 tile[64][65];
    const int b = blockIdx.z;
    const int d0 = blockIdx.x * 64;
    const int n0 = blockIdx.y * 64;
    const int t = threadIdx.x;
    const int tx = t & 15;
    const int ty = t >> 4;
    const float* ib = in + (size_t)b * NN * DD;
    bf16* xrb = xr + (size_t)b * NN * DD;
#pragma unroll
    for (int q = 0; q < 4; ++q) {
        const int n = n0 + ty + q * 16;
        f32x4 v = *(const f32x4*)&ib[(size_t)n * DD + d0 + tx * 4];
        bf16x4 p;
#pragma unroll
        for (int j = 0; j < 4; ++j) p[j] = (bf16)v[j];
        *(bf16x4*)&xrb[(size_t)n * DD + d0 + tx * 4] = p;
#pragma unroll
        for (int j = 0; j < 4; ++j) tile[ty + q * 16][tx * 4 + j] = p[j];
    }
    __syncthreads();
    bf16* xtb = xt + (size_t)b * DD * NN;
#pragma unroll
    for (int q = 0; q < 4; ++q) {
        const int d = ty + q * 16;
        bf16x4 p;
#pragma unroll
        for (int j = 0; j < 4; ++j) p[j] = tile[tx * 4 + j][d];
        *(bf16x4*)&xtb[(size_t)(d0 + d) * NN + n0 + tx * 4] = p;
    }
}

// ---------------------------------------------------------------------------
// Shared 128x128 bt-form MFMA tile loop
// ---------------------------------------------------------------------------
__device__ __forceinline__ void mfma_tile_loop(const bf16* __restrict__ A,
                                               const bf16* __restrict__ B,
                                               int lda, int ldb, int K,
                                               int i0, int j0,
                                               bf16* At, bf16* Bt, f32x4 acc[4][4]) {
    const int t = threadIdx.x;
    const int lane = t & 63;
    const int w = t >> 6;
    const int wr = w >> 1, wc = w & 1;
    const int srow = t >> 2;
    const int scol = (t & 3) * 8;
    const int fr = lane & 15;
    const int fk = (lane >> 4) * 8;
    for (int k0 = 0; k0 < K; k0 += 32) {
        __syncthreads();
        async_copy16(A + (size_t)(i0 + srow) * lda + k0 + scol, &At[t * 8]);
        async_copy16(A + (size_t)(i0 + 64 + srow) * lda + k0 + scol, &At[2048 + t * 8]);
        async_copy16(B + (size_t)(j0 + srow) * ldb + k0 + scol, &Bt[t * 8]);
        async_copy16(B + (size_t)(j0 + 64 + srow) * ldb + k0 + scol, &Bt[2048 + t * 8]);
        __syncthreads();
        bf16x8 af[4], bg[4];
#pragma unroll
        for (int mi = 0; mi < 4; ++mi)
            af[mi] = *(const bf16x8*)&At[(wr * 64 + mi * 16 + fr) * 32 + fk];
#pragma unroll
        for (int ni = 0; ni < 4; ++ni)
            bg[ni] = *(const bf16x8*)&Bt[(wc * 64 + ni * 16 + fr) * 32 + fk];
#pragma unroll
        for (int mi = 0; mi < 4; ++mi)
#pragma unroll
            for (int ni = 0; ni < 4; ++ni)
                acc[mi][ni] = __builtin_amdgcn_mfma_f32_16x16x32_bf16(
                    af[mi], bg[ni], acc[mi][ni], 0, 0, 0);
    }
}

// P2 = 2*S@S - I  (and P2T)
__global__ __launch_bounds__(256) void k_poly2(const bf16* __restrict__ Sb,
                                               const bf16* __restrict__ SbT,
                                               bf16* __restrict__ P2,
                                               bf16* __restrict__ P2T) {
    __shared__ bf16 At[4096] __attribute__((aligned(16)));
    __shared__ bf16 Bt[4096] __attribute__((aligned(16)));
    const int i0 = blockIdx.y * 128, j0 = blockIdx.x * 128;
    f32x4 acc[4][4];
#pragma unroll
    for (int mi = 0; mi < 4; ++mi)
#pragma unroll
        for (int ni = 0; ni < 4; ++ni) acc[mi][ni] = f32x4{0.f, 0.f, 0.f, 0.f};
    mfma_tile_loop(Sb, SbT, NN, NN, NN, i0, j0, At, Bt, acc);
    const int t = threadIdx.x, lane = t & 63, w = t >> 6;
    const int wr = w >> 1, wc = w & 1;
    const int fr = lane & 15, rb = (lane >> 4) * 4;
#pragma unroll
    for (int mi = 0; mi < 4; ++mi)
#pragma unroll
        for (int ni = 0; ni < 4; ++ni) {
            const int ii = i0 + wr * 64 + mi * 16 + rb;
            const int jj = j0 + wc * 64 + ni * 16 + fr;
#pragma unroll
            for (int tt = 0; tt < 4; ++tt) {
                float v = 2.f * acc[mi][ni][tt] - ((ii + tt) == jj ? 1.f : 0.f);
                bf16 bv = (bf16)v;
                P2[(size_t)(ii + tt) * NN + jj] = bv;
                P2T[(size_t)jj * NN + (ii + tt)] = bv;
            }
        }
}

// P3 = 2*S@P2 - S
__global__ __launch_bounds__(256) void k_poly3(const bf16* __restrict__ Sb,
                                               const bf16* __restrict__ P2T,
                                               bf16* __restrict__ P3) {
    __shared__ bf16 At[4096] __attribute__((aligned(16)));
    __shared__ bf16 Bt[4096] __attribute__((aligned(16)));
    const int i0 = blockIdx.y * 128, j0 = blockIdx.x * 128;
    f32x4 acc[4][4];
#pragma unroll
    for (int mi = 0; mi < 4; ++mi)
#pragma unroll
        for (int ni = 0; ni < 4; ++ni) acc[mi][ni] = f32x4{0.f, 0.f, 0.f, 0.f};
    mfma_tile_loop(Sb, P2T, NN, NN, NN, i0, j0, At, Bt, acc);
    const int t = threadIdx.x, lane = t & 63, w = t >> 6;
    const int wr = w >> 1, wc = w & 1;
    const int fr = lane & 15, rb = (lane >> 4) * 4;
#pragma unroll
    for (int mi = 0; mi < 4; ++mi)
#pragma unroll
        for (int ni = 0; ni < 4; ++ni) {
            const int ii = i0 + wr * 64 + mi * 16 + rb;
            const int jj = j0 + wc * 64 + ni * 16 + fr;
#pragma unroll
            for (int tt = 0; tt < 4; ++tt) {
                float v = 2.f * acc[mi][ni][tt] - (float)Sb[(size_t)(ii + tt) * NN + jj];
                P3[(size_t)(ii + tt) * NN + jj] = (bf16)v;
            }
        }
}

// Xr[m][b][n][d] = sum_k P_m[n][k] * XT0[b][d][k];  P_m at Pbase + 2*m*NN*NN
__global__ __launch_bounds__(256) void k_apply(const bf16* __restrict__ P,
                                               const bf16* __restrict__ XT0,
                                               bf16* __restrict__ Xr) {
    __shared__ bf16 At[4096] __attribute__((aligned(16)));
    __shared__ bf16 Bt[4096] __attribute__((aligned(16)));
    __shared__ bf16 epi[32 * 136] __attribute__((aligned(16)));
    const int z = blockIdx.z;
    const int m = z >> 5;
    const int b = z & 31;
    const int i0 = blockIdx.y * 128;  // n
    const int j0 = blockIdx.x * 128;  // d
    const bf16* A = P + (size_t)(2 * m) * NN * NN;  // Sb -> P2 -> P3 (stride 2 slots)
    const bf16* B = XT0 + (size_t)b * DD * NN;
    f32x4 acc[4][4];
#pragma unroll
    for (int mi = 0; mi < 4; ++mi)
#pragma unroll
        for (int ni = 0; ni < 4; ++ni) acc[mi][ni] = f32x4{0.f, 0.f, 0.f, 0.f};
    mfma_tile_loop(A, B, NN, NN, NN, i0, j0, At, Bt, acc);

    bf16* ob = Xr + ((size_t)m * BB + b) * NN * DD;
    const int t = threadIdx.x, lane = t & 63, w = t >> 6;
    const int wr = w >> 1, wc = w & 1;
    const int fr = lane & 15, rb = (lane >> 4) * 4;
#pragma unroll
    for (int mi = 0; mi < 4; ++mi) {
        __syncthreads();
#pragma unroll
        for (int ni = 0; ni < 4; ++ni) {
            const int col = wc * 64 + ni * 16 + fr;
#pragma unroll
            for (int tt = 0; tt < 4; ++tt) {
                const int lr = wr * 16 + rb + tt;
                epi[lr * 136 + col] = (bf16)acc[mi][ni][tt];
            }
        }
        __syncthreads();
#pragma unroll
        for (int it = 0; it < 2; ++it) {
            const int idx = t + it * 256;
            const int lr = idx >> 4;
            const int cq = idx & 15;
            bf16x8 vv = *(const bf16x8*)&epi[lr * 136 + cq * 8];
            const int gr = i0 + (lr >> 4) * 64 + mi * 16 + (lr & 15);
            *(bf16x8*)&ob[(size_t)gr * DD + j0 + cq * 8] = vv;
        }
    }
}

// out[bn][o] = sum_s sum_d Xr_s[bn][d] * Wt[s][o][d] + bias[o]
__global__ __launch_bounds__(256) void k_final(const bf16* __restrict__ Xr,
                                               const bf16* __restrict__ Wt,
                                               const float* __restrict__ bias,
                                               float* __restrict__ out) {
    __shared__ bf16 At[4096] __attribute__((aligned(16)));
    __shared__ bf16 Bt[4096] __attribute__((aligned(16)));
    const int wgid = blockIdx.y * gridDim.x + blockIdx.x;  // 0..767
    const int swz = (wgid & 7) * 96 + (wgid >> 3);         // bijective XCD swizzle
    const int i0 = (swz / 6) * 128;  // bn rows
    const int j0 = (swz % 6) * 128;  // o cols
    const int t = threadIdx.x;
    const int lane = t & 63;
    const int w = t >> 6;
    const int wr = w >> 1, wc = w & 1;
    const int srow = t >> 2;
    const int scol = (t & 3) * 8;
    const int fr = lane & 15;
    const int fk = (lane >> 4) * 8;

    f32x4 acc[4][4];
#pragma unroll
    for (int mi = 0; mi < 4; ++mi)
#pragma unroll
        for (int ni = 0; ni < 4; ++ni) acc[mi][ni] = f32x4{0.f, 0.f, 0.f, 0.f};

    for (int s = 0; s < 4; ++s) {
        const bf16* As = Xr + (size_t)s * BB * NN * DD;
        const bf16* Bs = Wt + (size_t)s * DD * DD;
        for (int k0 = 0; k0 < DD; k0 += 32) {
            __syncthreads();
            async_copy16(As + (size_t)(i0 + srow) * DD + k0 + scol, &At[t * 8]);
            async_copy16(As + (size_t)(i0 + 64 + srow) * DD + k0 + scol, &At[2048 + t * 8]);
            async_copy16(Bs + (size_t)(j0 + srow) * DD + k0 + scol, &Bt[t * 8]);
            async_copy16(Bs + (size_t)(j0 + 64 + srow) * DD + k0 + scol, &Bt[2048 + t * 8]);
            __syncthreads();
            bf16x8 af[4], bg[4];
#pragma unroll
            for (int mi = 0; mi < 4; ++mi)
                af[mi] = *(const bf16x8*)&At[(wr * 64 + mi * 16 + fr) * 32 + fk];
#pragma unroll
            for (int ni = 0; ni < 4; ++ni)
                bg[ni] = *(const bf16x8*)&Bt[(wc * 64 + ni * 16 + fr) * 32 + fk];
#pragma unroll
            for (int mi = 0; mi < 4; ++mi)
#pragma unroll
                for (int ni = 0; ni < 4; ++ni)
                    acc[mi][ni] = __builtin_amdgcn_mfma_f32_16x16x32_bf16(
                        af[mi], bg[ni], acc[mi][ni], 0, 0, 0);
        }
    }

    const int rb = (lane >> 4) * 4;
#pragma unroll
    for (int ni = 0; ni < 4; ++ni) {
        const int jj = j0 + wc * 64 + ni * 16 + fr;
        const float bv = bias[jj];
#pragma unroll
        for (int mi = 0; mi < 4; ++mi) {
            const int ii = i0 + wr * 64 + mi * 16 + rb;
#pragma unroll
            for (int tt = 0; tt < 4; ++tt)
                out[(size_t)(ii + tt) * DD + jj] = acc[mi][ni][tt] + bv;
        }
    }
}

// ---------------------------------------------------------------------------
// Launch
// ---------------------------------------------------------------------------
extern "C" void kernel_launch(void* const* d_in, const int* in_sizes, int n_in,
                              void* d_out, int out_size, void* d_ws, size_t ws_size,
                              hipStream_t stream) {
    const float* inputs = (const float*)d_in[0];   // [32,512,768]
    const float* adj = (const float*)d_in[1];      // [512,512]
    const float* weights = (const float*)d_in[2];  // [3072,768]
    const float* biases = (const float*)d_in[3];   // [768]
    float* out = (float*)d_out;                    // [32,512,768]

    char* ws = (char*)d_ws;
    const size_t SQ = (size_t)NN * NN * 2;         // 512 KiB
    const size_t SLAB = (size_t)BB * NN * DD * 2;  // 24 MiB
    float* dv = (float*)(ws + 0);
    // P-slot layout (stride SQ): [Sb][SbT][P2][P2T][P3]  -> Sb,P2,P3 at even slots
    bf16* Sb = (bf16*)(ws + 4096);
    bf16* SbT = (bf16*)(ws + 4096 + SQ);
    bf16* P2 = (bf16*)(ws + 4096 + 2 * SQ);
    bf16* P2T = (bf16*)(ws + 4096 + 3 * SQ);
    bf16* P3 = (bf16*)(ws + 4096 + 4 * SQ);
    bf16* Wt = (bf16*)(ws + 4096 + 5 * SQ);        // 4.5 MiB
    char* slabBase = ws + 4096 + 5 * SQ + (size_t)4 * DD * DD * 2;
    bf16* XT0 = (bf16*)(slabBase);
    bf16* Xr0 = (bf16*)(slabBase + SLAB);          // Xr0..Xr3 contiguous
    bf16* Xr1 = (bf16*)(slabBase + 2 * SLAB);
    // total ~127 MiB (< the >=149 MiB confirmed available in round 1)

    k_rowsum<<<NN, 64, 0, stream>>>(adj, dv);
    k_support2<<<dim3(16, 16), dim3(32, 8), 0, stream>>>(adj, dv, Sb, SbT);
    k_prepwt2<<<dim3(24, 24, 4), dim3(32, 8), 0, stream>>>(weights, Wt);
    k_prepx<<<dim3(DD / 64, NN / 64, BB), 256, 0, stream>>>(inputs, Xr0, XT0);

    k_poly2<<<dim3(4, 4), 256, 0, stream>>>(Sb, SbT, P2, P2T);
    k_poly3<<<dim3(4, 4), 256, 0, stream>>>(Sb, P2T, P3);

    k_apply<<<dim3(DD / 128, NN / 128, 3 * BB), 256, 0, stream>>>(Sb, XT0, Xr1);

    k_final<<<dim3(DD / 128, (BB * NN) / 128), 256, 0, stream>>>(Xr0, Wt, biases, out);
}